// Round 10
// baseline (218.462 us; speedup 1.0000x reference)
//
#include <hip/hip_runtime.h>

// MultiHeadSelfAttention: B=4, N=2048, D=1024, H=16, Hd=64
// bf16 MFMA everywhere. Attention: 4-wave blocks, 32 q-rows/wave (grid 1024 =
// 4 blocks/CU supply), K/V staged via global_load_lds (src-side XOR swizzle,
// double-buffered, 1 barrier/tile), swapped-operand 32x32x16 MFMA, max-free
// softmax (P = exp2(s); 2^-m cancels in O/l), V^T stored with key-columns
// bit2<->bit3 permuted so lane-own s-values ARE the PV B-fragment.
// Register-dieted (ls[4], chunked vf, launch_bounds(256,3)) for 3 waves/SIMD.

typedef __attribute__((ext_vector_type(8))) short bf16x8;
typedef __attribute__((ext_vector_type(4))) short s16x4;
typedef __attribute__((ext_vector_type(4))) float f32x4;
typedef __attribute__((ext_vector_type(16))) float f32x16;
typedef __attribute__((ext_vector_type(4))) unsigned u32x4;

#define LOG2E 1.44269504088896340736f

__device__ static inline short f2bf(float f) {
  unsigned u = __builtin_bit_cast(unsigned, f);
  unsigned r = (u + 0x7fffu + ((u >> 16) & 1u)) >> 16;
  return (short)r;
}
__device__ static inline unsigned cvtpk_bf16(float lo, float hi) {
  unsigned r;
  asm("v_cvt_pk_bf16_f32 %0, %1, %2" : "=v"(r) : "v"(lo), "v"(hi));
  return r;
}

__device__ static inline void gload_lds16(const void* g, void* l) {
  __builtin_amdgcn_global_load_lds(
      (const __attribute__((address_space(1))) void*)g,
      (__attribute__((address_space(3))) void*)l, 16, 0, 0);
}

// ---------------- fp32 -> bf16 convert ----------------
__global__ void cvt_f32_bf16(const float* __restrict__ in, short* __restrict__ out, int n4) {
  int i = blockIdx.x * 256 + threadIdx.x;
  if (i < n4) {
    float4 v = ((const float4*)in)[i];
    s16x4 o4 = { f2bf(v.x), f2bf(v.y), f2bf(v.z), f2bf(v.w) };
    ((s16x4*)out)[i] = o4;
  }
}

// ---------------- GEMM C = A[M,K] * B[N,K]^T (+bias) ----------------
// EPI=0: scatter q (pre-scaled 0.125*log2e), k as [B,H,N,Hd]; v as [B,H,Hd,N]
//        with key-position bits 2,3 swapped (PV B-frag pre-permutation).
// EPI=1: fp32 out + bias.
template <int EPI>
__global__ __launch_bounds__(256, 2) void gemm_bt(
    const short* __restrict__ A, const short* __restrict__ Bm,
    const float* __restrict__ bias, int K,
    short* __restrict__ qo, short* __restrict__ ko, short* __restrict__ vto,
    float* __restrict__ outf) {
  __shared__ __align__(16) char smem[16384];
  char* As = smem;
  char* Bs = smem + 8192;
  const int tid = threadIdx.x, lane = tid & 63, w = tid >> 6;
  const int wm = w >> 1, wn = w & 1;
  const int bm = blockIdx.y, bn = blockIdx.x;

  f32x4 acc[4][4];
  const f32x4 z4 = {0.f, 0.f, 0.f, 0.f};
#pragma unroll
  for (int m = 0; m < 4; ++m)
#pragma unroll
    for (int n = 0; n < 4; ++n) acc[m][n] = z4;

  const short* Abase = A + (size_t)bm * 128 * K;
  const short* Bbase = Bm + (size_t)bn * 128 * K;

  for (int k0 = 0; k0 < K; k0 += 32) {
#pragma unroll
    for (int j = 0; j < 2; ++j) {
      int ia = w * 2 + j;
      int row = ia * 16 + (lane >> 2);
      int cl = (lane & 3) ^ (row & 3);
      gload_lds16(Abase + (size_t)row * K + k0 + cl * 8, As + ia * 1024);
      gload_lds16(Bbase + (size_t)row * K + k0 + cl * 8, Bs + ia * 1024);
    }
    __syncthreads();

    bf16x8 af[4], bf[4];
#pragma unroll
    for (int m = 0; m < 4; ++m) {
      int r = wm * 64 + m * 16 + (lane & 15);
      af[m] = *(const bf16x8*)(As + r * 64 + ((((lane >> 4)) ^ (r & 3)) << 4));
    }
#pragma unroll
    for (int n = 0; n < 4; ++n) {
      int r = wn * 64 + n * 16 + (lane & 15);
      bf[n] = *(const bf16x8*)(Bs + r * 64 + ((((lane >> 4)) ^ (r & 3)) << 4));
    }
#pragma unroll
    for (int m = 0; m < 4; ++m)
#pragma unroll
      for (int n = 0; n < 4; ++n)
        acc[m][n] = __builtin_amdgcn_mfma_f32_16x16x32_bf16(af[m], bf[n], acc[m][n], 0, 0, 0);
    __syncthreads();
  }

  if (EPI == 0) {
    const int which = bn >> 3;               // 0=q 1=k 2=v
    const int hh = ((bn & 7) << 1) | wn;     // head
    const int bidx = bm >> 4;                // batch
    const size_t bh = (size_t)bidx * 16 + hh;
#pragma unroll
    for (int nf = 0; nf < 4; ++nf) {
      int dd = nf * 16 + (lane & 15);
      float bv = bias[bn * 128 + wn * 64 + dd];
#pragma unroll
      for (int m = 0; m < 4; ++m) {
        int nr0 = (bm & 15) * 128 + wm * 64 + m * 16 + ((lane >> 4) << 2);
        if (which == 2) {
          // key-position permutation: swap bits 2,3 of key index
          int nper = (nr0 & ~12) | ((nr0 & 4) << 1) | ((nr0 & 8) >> 1);
          s16x4 pk;
#pragma unroll
          for (int r = 0; r < 4; ++r) pk[r] = f2bf(acc[m][nf][r] + bv);
          *(s16x4*)(vto + (bh * 64 + dd) * 2048 + nper) = pk;
        } else if (which == 0) {
          short* dst = qo + (bh * 2048 + nr0) * 64 + dd;
#pragma unroll
          for (int r = 0; r < 4; ++r)
            dst[(size_t)r * 64] = f2bf((acc[m][nf][r] + bv) * (0.125f * LOG2E));
        } else {
          short* dst = ko + (bh * 2048 + nr0) * 64 + dd;
#pragma unroll
          for (int r = 0; r < 4; ++r) dst[(size_t)r * 64] = f2bf(acc[m][nf][r] + bv);
        }
      }
    }
  } else {
#pragma unroll
    for (int nf = 0; nf < 4; ++nf) {
      int gn = bn * 128 + wn * 64 + nf * 16 + (lane & 15);
      float bv = bias[gn];
#pragma unroll
      for (int m = 0; m < 4; ++m) {
        int gm0 = bm * 128 + wm * 64 + m * 16 + ((lane >> 4) << 2);
        float* dst = outf + (size_t)gm0 * 1024 + gn;
#pragma unroll
        for (int r = 0; r < 4; ++r) dst[(size_t)r * 1024] = acc[m][nf][r] + bv;
      }
    }
  }
}

// two PV B-frags (K=16 each) from one exp'd s-vector (V pre-permuted)
#define BUILD_PF2(d0, d1, sv)                                                  \
  {                                                                            \
    u32x4 w0_ = {cvtpk_bf16(sv[0], sv[1]), cvtpk_bf16(sv[2], sv[3]),           \
                 cvtpk_bf16(sv[4], sv[5]), cvtpk_bf16(sv[6], sv[7])};          \
    d0 = __builtin_bit_cast(bf16x8, w0_);                                      \
    u32x4 w1_ = {cvtpk_bf16(sv[8], sv[9]), cvtpk_bf16(sv[10], sv[11]),         \
                 cvtpk_bf16(sv[12], sv[13]), cvtpk_bf16(sv[14], sv[15])};      \
    d1 = __builtin_bit_cast(bf16x8, w1_);                                      \
  }

// ---------------- flash attention, LDS-shared K/V, 32 q/wave ----------------
__global__ __launch_bounds__(256, 3) void attn_kernel(
    const short* __restrict__ q, const short* __restrict__ kk,
    const short* __restrict__ vt, short* __restrict__ ao) {
  __shared__ __align__(16) char smem[32768];  // 2 bufs x (K 8KB + V 8KB)
  const int tid = threadIdx.x, lane = tid & 63, w = tid >> 6;
  const int r31 = lane & 31, h = lane >> 5;
  const int id = blockIdx.x;
  const int xcd = id & 7, p = id >> 3;
  const int bh = xcd * 8 + (p >> 4);   // 8 bh per XCD -> K/V L2-resident
  const int qblk = p & 15;
  const int q0 = qblk * 128 + w * 32;  // wave owns q0..q0+31

  const short* qptr = q + ((size_t)bh * 2048 + q0 + r31) * 64 + h * 8;
  const short* kgl = kk + (size_t)bh * 2048 * 64;   // [2048][64]
  const short* vgl = vt + (size_t)bh * 64 * 2048;   // V^T [64][2048] (perm'd cols)

  // staging: thread stages rows srow, srow+8; source col pre-swizzled so LDS
  // image is [row][col ^ ((row&7)<<4)].
  const int srow = w * 16 + (lane >> 3);
  const int scol = ((lane & 7) * 8) ^ ((lane >> 3) << 3);  // shorts
  const int ldst = w * 2048;                               // bytes, +j*1024

  // Q fragments (pre-scaled by 0.125*log2e)
  bf16x8 qf[4];
#pragma unroll
  for (int dk = 0; dk < 4; ++dk) qf[dk] = *(const bf16x8*)(qptr + dk * 16);

  f32x16 o0, o1;
#pragma unroll
  for (int e = 0; e < 16; ++e) { o0[e] = 0.f; o1[e] = 0.f; }
  float ls[4];
#pragma unroll
  for (int e = 0; e < 4; ++e) ls[e] = 0.f;

  // prologue: stage tile 0 into buf 0
#pragma unroll
  for (int j = 0; j < 2; ++j) {
    gload_lds16(kgl + (size_t)(srow + j * 8) * 64 + scol, smem + ldst + j * 1024);
    gload_lds16(vgl + (size_t)(srow + j * 8) * 2048 + scol, smem + 8192 + ldst + j * 1024);
  }
  __syncthreads();

  int cur = 0;
  for (int t = 0; t < 2048; t += 64) {
    const char* Kb = smem + cur * 16384;
    const char* Vb = smem + cur * 16384 + 8192;

    // ---- prefetch next tile into other buffer ----
    if (t + 64 < 2048) {
      char* nb = (char*)smem + (cur ^ 1) * 16384;
#pragma unroll
      for (int j = 0; j < 2; ++j) {
        gload_lds16(kgl + (size_t)(t + 64 + srow + j * 8) * 64 + scol, nb + ldst + j * 1024);
        gload_lds16(vgl + (size_t)(srow + j * 8) * 2048 + (t + 64) + scol, nb + 8192 + ldst + j * 1024);
      }
    }

    // ---- K fragments from LDS (swizzled, conflict-free) ----
    bf16x8 kf0[4], kf1[4];
#pragma unroll
    for (int dk = 0; dk < 4; ++dk) {
      int cb = (dk * 32 + h * 16) ^ ((r31 & 7) << 4);
      kf0[dk] = *(const bf16x8*)(Kb + r31 * 128 + cb);
      kf1[dk] = *(const bf16x8*)(Kb + (32 + r31) * 128 + cb);
    }

    // ---- QK^T: S^T[k][q], two 32-key blocks (interleaved chains) ----
    f32x16 s0, s1;
#pragma unroll
    for (int e = 0; e < 16; ++e) { s0[e] = 0.f; s1[e] = 0.f; }
#pragma unroll
    for (int dk = 0; dk < 4; ++dk) {
      s0 = __builtin_amdgcn_mfma_f32_32x32x16_bf16(kf0[dk], qf[dk], s0, 0, 0, 0);
      s1 = __builtin_amdgcn_mfma_f32_32x32x16_bf16(kf1[dk], qf[dk], s1, 0, 0, 0);
    }

    // ---- max-free softmax: P = exp2(s); accumulate l partials (4 regs) ----
#pragma unroll
    for (int e = 0; e < 16; ++e) {
      s0[e] = __builtin_exp2f(s0[e]);
      s1[e] = __builtin_exp2f(s1[e]);
    }
#pragma unroll
    for (int e = 0; e < 4; ++e) {
      float t0 = (s0[e] + s0[e + 4]) + (s0[e + 8] + s0[e + 12]);
      float t1 = (s1[e] + s1[e + 4]) + (s1[e + 8] + s1[e + 12]);
      ls[e] += t0 + t1;
    }

    // ---- P^T B-frags: direct cvt_pk (V pre-permuted; no exchange) ----
    bf16x8 pf0, pf1, pf2, pf3;
    BUILD_PF2(pf0, pf1, s0);
    BUILD_PF2(pf2, pf3, s1);

    // ---- O^T += V^T . P^T (vf in 2 chunks to cap live regs) ----
    {
      bf16x8 v00, v10, v01, v11;
      int cb0 = (0 * 32 + h * 16) ^ ((r31 & 7) << 4);
      int cb1 = (1 * 32 + h * 16) ^ ((r31 & 7) << 4);
      v00 = *(const bf16x8*)(Vb + r31 * 128 + cb0);
      v10 = *(const bf16x8*)(Vb + (32 + r31) * 128 + cb0);
      v01 = *(const bf16x8*)(Vb + r31 * 128 + cb1);
      v11 = *(const bf16x8*)(Vb + (32 + r31) * 128 + cb1);
      o0 = __builtin_amdgcn_mfma_f32_32x32x16_bf16(v00, pf0, o0, 0, 0, 0);
      o1 = __builtin_amdgcn_mfma_f32_32x32x16_bf16(v10, pf0, o1, 0, 0, 0);
      o0 = __builtin_amdgcn_mfma_f32_32x32x16_bf16(v01, pf1, o0, 0, 0, 0);
      o1 = __builtin_amdgcn_mfma_f32_32x32x16_bf16(v11, pf1, o1, 0, 0, 0);
    }
    {
      bf16x8 v02, v12, v03, v13;
      int cb2 = (2 * 32 + h * 16) ^ ((r31 & 7) << 4);
      int cb3 = (3 * 32 + h * 16) ^ ((r31 & 7) << 4);
      v02 = *(const bf16x8*)(Vb + r31 * 128 + cb2);
      v12 = *(const bf16x8*)(Vb + (32 + r31) * 128 + cb2);
      v03 = *(const bf16x8*)(Vb + r31 * 128 + cb3);
      v13 = *(const bf16x8*)(Vb + (32 + r31) * 128 + cb3);
      o0 = __builtin_amdgcn_mfma_f32_32x32x16_bf16(v02, pf2, o0, 0, 0, 0);
      o1 = __builtin_amdgcn_mfma_f32_32x32x16_bf16(v12, pf2, o1, 0, 0, 0);
      o0 = __builtin_amdgcn_mfma_f32_32x32x16_bf16(v03, pf3, o0, 0, 0, 0);
      o1 = __builtin_amdgcn_mfma_f32_32x32x16_bf16(v13, pf3, o1, 0, 0, 0);
    }

    __syncthreads();
    cur ^= 1;
  }

  // ---- epilogue: l tree + O/l -> ao bf16 [B,N,D] ----
  float lsum = (ls[0] + ls[1]) + (ls[2] + ls[3]);
  lsum += __shfl_xor(lsum, 32);

  const int b = bh >> 4, hd = bh & 15;
  float inv = 1.f / lsum;
  short* orow = ao + ((size_t)b * 2048 + q0 + r31) * 1024 + hd * 64;
#pragma unroll
  for (int s2 = 0; s2 < 4; ++s2) {
    s16x4 pk0, pk1;
#pragma unroll
    for (int r = 0; r < 4; ++r) {
      pk0[r] = f2bf(o0[4 * s2 + r] * inv);   // d = 8*s2 + 4*h + r
      pk1[r] = f2bf(o1[4 * s2 + r] * inv);   // d+32
    }
    *(s16x4*)(orow + 8 * s2 + 4 * h) = pk0;
    *(s16x4*)(orow + 32 + 8 * s2 + 4 * h) = pk1;
  }
}

// ---------------- launch ----------------
extern "C" void kernel_launch(void* const* d_in, const int* in_sizes, int n_in,
                              void* d_out, int out_size, void* d_ws, size_t ws_size,
                              hipStream_t stream) {
  const float* x = (const float*)d_in[0];
  const float* qkv_w = (const float*)d_in[1];
  const float* qkv_b = (const float*)d_in[2];
  const float* proj_w = (const float*)d_in[3];
  const float* proj_b = (const float*)d_in[4];
  float* out = (float*)d_out;

  char* ws = (char*)d_ws;
  short* xb    = (short*)(ws + 0);          // 16 MB  [8192][1024]
  short* wqkv  = (short*)(ws + 16777216);   // 6 MB   [3072][1024]
  short* wproj = (short*)(ws + 23068672);   // 2 MB   [1024][1024]
  short* qb    = (short*)(ws + 25165824);   // 16 MB  [B,H,N,Hd]
  short* kb    = (short*)(ws + 41943040);   // 16 MB  [B,H,N,Hd]
  short* vtb   = (short*)(ws + 58720256);   // 16 MB  [B,H,Hd,N] (perm'd cols)
  short* aob   = (short*)(ws + 75497472);   // 16 MB  [B,N,D]

  cvt_f32_bf16<<<8192, 256, 0, stream>>>(x, xb, 2097152);
  cvt_f32_bf16<<<3072, 256, 0, stream>>>(qkv_w, wqkv, 786432);
  cvt_f32_bf16<<<1024, 256, 0, stream>>>(proj_w, wproj, 262144);

  gemm_bt<0><<<dim3(24, 64), 256, 0, stream>>>(xb, wqkv, qkv_b, 1024, qb, kb, vtb, nullptr);
  attn_kernel<<<1024, 256, 0, stream>>>(qb, kb, vtb, aob);
  gemm_bt<1><<<dim3(8, 64), 256, 0, stream>>>(aob, wproj, proj_b, 1024, nullptr, nullptr, nullptr, out);
}

// Round 11
// 198.890 us; speedup vs baseline: 1.0984x; 1.0984x over previous
//
#include <hip/hip_runtime.h>

// MultiHeadSelfAttention: B=4, N=2048, D=1024, H=16, Hd=64
// bf16 MFMA everywhere. Attention: 4-wave blocks, 32 q-rows/wave, K/V staged
// via global_load_lds (src-side XOR swizzle, double-buffered, 1 barrier/tile),
// swapped-operand 32x32x16 MFMA, max-free softmax (P = exp2(s); 2^-m cancels
// in O/l) with HARDWARE v_exp_f32 (builtin_exp2f w/o fast-math expands to a
// ~12-op precise sequence -- the hidden VALU hog of rounds 3-10), V^T stored
// with key-columns bit2<->bit3 permuted so lane-own s-values ARE the PV
// B-fragment, XCD-affinity swizzle.

typedef __attribute__((ext_vector_type(8))) short bf16x8;
typedef __attribute__((ext_vector_type(4))) short s16x4;
typedef __attribute__((ext_vector_type(4))) float f32x4;
typedef __attribute__((ext_vector_type(16))) float f32x16;
typedef __attribute__((ext_vector_type(4))) unsigned u32x4;

#define LOG2E 1.44269504088896340736f

__device__ static inline short f2bf(float f) {
  unsigned u = __builtin_bit_cast(unsigned, f);
  unsigned r = (u + 0x7fffu + ((u >> 16) & 1u)) >> 16;
  return (short)r;
}
__device__ static inline unsigned cvtpk_bf16(float lo, float hi) {
  unsigned r;
  asm("v_cvt_pk_bf16_f32 %0, %1, %2" : "=v"(r) : "v"(lo), "v"(hi));
  return r;
}
// hardware 2^x (v_exp_f32). backend tracks TRANS hazards for the builtin.
__device__ static inline float exp2_hw(float x) {
#if __has_builtin(__builtin_amdgcn_exp2f)
  return __builtin_amdgcn_exp2f(x);
#else
  float r;
  asm("v_exp_f32 %0, %1" : "=v"(r) : "v"(x));
  return r;
#endif
}

__device__ static inline void gload_lds16(const void* g, void* l) {
  __builtin_amdgcn_global_load_lds(
      (const __attribute__((address_space(1))) void*)g,
      (__attribute__((address_space(3))) void*)l, 16, 0, 0);
}

// ---------------- fp32 -> bf16 convert ----------------
__global__ void cvt_f32_bf16(const float* __restrict__ in, short* __restrict__ out, int n4) {
  int i = blockIdx.x * 256 + threadIdx.x;
  if (i < n4) {
    float4 v = ((const float4*)in)[i];
    s16x4 o4 = { f2bf(v.x), f2bf(v.y), f2bf(v.z), f2bf(v.w) };
    ((s16x4*)out)[i] = o4;
  }
}

// ---------------- GEMM C = A[M,K] * B[N,K]^T (+bias) ----------------
// EPI=0: scatter q (pre-scaled 0.125*log2e), k as [B,H,N,Hd]; v as [B,H,Hd,N]
//        with key-position bits 2,3 swapped (PV B-frag pre-permutation).
// EPI=1: fp32 out + bias.
template <int EPI>
__global__ __launch_bounds__(256, 2) void gemm_bt(
    const short* __restrict__ A, const short* __restrict__ Bm,
    const float* __restrict__ bias, int K,
    short* __restrict__ qo, short* __restrict__ ko, short* __restrict__ vto,
    float* __restrict__ outf) {
  __shared__ __align__(16) char smem[16384];
  char* As = smem;
  char* Bs = smem + 8192;
  const int tid = threadIdx.x, lane = tid & 63, w = tid >> 6;
  const int wm = w >> 1, wn = w & 1;
  const int bm = blockIdx.y, bn = blockIdx.x;

  f32x4 acc[4][4];
  const f32x4 z4 = {0.f, 0.f, 0.f, 0.f};
#pragma unroll
  for (int m = 0; m < 4; ++m)
#pragma unroll
    for (int n = 0; n < 4; ++n) acc[m][n] = z4;

  const short* Abase = A + (size_t)bm * 128 * K;
  const short* Bbase = Bm + (size_t)bn * 128 * K;

  for (int k0 = 0; k0 < K; k0 += 32) {
#pragma unroll
    for (int j = 0; j < 2; ++j) {
      int ia = w * 2 + j;
      int row = ia * 16 + (lane >> 2);
      int cl = (lane & 3) ^ (row & 3);
      gload_lds16(Abase + (size_t)row * K + k0 + cl * 8, As + ia * 1024);
      gload_lds16(Bbase + (size_t)row * K + k0 + cl * 8, Bs + ia * 1024);
    }
    __syncthreads();

    bf16x8 af[4], bf[4];
#pragma unroll
    for (int m = 0; m < 4; ++m) {
      int r = wm * 64 + m * 16 + (lane & 15);
      af[m] = *(const bf16x8*)(As + r * 64 + ((((lane >> 4)) ^ (r & 3)) << 4));
    }
#pragma unroll
    for (int n = 0; n < 4; ++n) {
      int r = wn * 64 + n * 16 + (lane & 15);
      bf[n] = *(const bf16x8*)(Bs + r * 64 + ((((lane >> 4)) ^ (r & 3)) << 4));
    }
#pragma unroll
    for (int m = 0; m < 4; ++m)
#pragma unroll
      for (int n = 0; n < 4; ++n)
        acc[m][n] = __builtin_amdgcn_mfma_f32_16x16x32_bf16(af[m], bf[n], acc[m][n], 0, 0, 0);
    __syncthreads();
  }

  if (EPI == 0) {
    const int which = bn >> 3;               // 0=q 1=k 2=v
    const int hh = ((bn & 7) << 1) | wn;     // head
    const int bidx = bm >> 4;                // batch
    const size_t bh = (size_t)bidx * 16 + hh;
#pragma unroll
    for (int nf = 0; nf < 4; ++nf) {
      int dd = nf * 16 + (lane & 15);
      float bv = bias[bn * 128 + wn * 64 + dd];
#pragma unroll
      for (int m = 0; m < 4; ++m) {
        int nr0 = (bm & 15) * 128 + wm * 64 + m * 16 + ((lane >> 4) << 2);
        if (which == 2) {
          // key-position permutation: swap bits 2,3 of key index
          int nper = (nr0 & ~12) | ((nr0 & 4) << 1) | ((nr0 & 8) >> 1);
          s16x4 pk;
#pragma unroll
          for (int r = 0; r < 4; ++r) pk[r] = f2bf(acc[m][nf][r] + bv);
          *(s16x4*)(vto + (bh * 64 + dd) * 2048 + nper) = pk;
        } else if (which == 0) {
          short* dst = qo + (bh * 2048 + nr0) * 64 + dd;
#pragma unroll
          for (int r = 0; r < 4; ++r)
            dst[(size_t)r * 64] = f2bf((acc[m][nf][r] + bv) * (0.125f * LOG2E));
        } else {
          short* dst = ko + (bh * 2048 + nr0) * 64 + dd;
#pragma unroll
          for (int r = 0; r < 4; ++r) dst[(size_t)r * 64] = f2bf(acc[m][nf][r] + bv);
        }
      }
    }
  } else {
#pragma unroll
    for (int nf = 0; nf < 4; ++nf) {
      int gn = bn * 128 + wn * 64 + nf * 16 + (lane & 15);
      float bv = bias[gn];
#pragma unroll
      for (int m = 0; m < 4; ++m) {
        int gm0 = bm * 128 + wm * 64 + m * 16 + ((lane >> 4) << 2);
        float* dst = outf + (size_t)gm0 * 1024 + gn;
#pragma unroll
        for (int r = 0; r < 4; ++r) dst[(size_t)r * 1024] = acc[m][nf][r] + bv;
      }
    }
  }
}

// two PV B-frags (K=16 each) from one exp'd s-vector (V pre-permuted)
#define BUILD_PF2(d0, d1, sv)                                                  \
  {                                                                            \
    u32x4 w0_ = {cvtpk_bf16(sv[0], sv[1]), cvtpk_bf16(sv[2], sv[3]),           \
                 cvtpk_bf16(sv[4], sv[5]), cvtpk_bf16(sv[6], sv[7])};          \
    d0 = __builtin_bit_cast(bf16x8, w0_);                                      \
    u32x4 w1_ = {cvtpk_bf16(sv[8], sv[9]), cvtpk_bf16(sv[10], sv[11]),         \
                 cvtpk_bf16(sv[12], sv[13]), cvtpk_bf16(sv[14], sv[15])};      \
    d1 = __builtin_bit_cast(bf16x8, w1_);                                      \
  }

// ---------------- flash attention, LDS-shared K/V, 32 q/wave ----------------
__global__ __launch_bounds__(256, 3) void attn_kernel(
    const short* __restrict__ q, const short* __restrict__ kk,
    const short* __restrict__ vt, short* __restrict__ ao) {
  __shared__ __align__(16) char smem[32768];  // 2 bufs x (K 8KB + V 8KB)
  const int tid = threadIdx.x, lane = tid & 63, w = tid >> 6;
  const int r31 = lane & 31, h = lane >> 5;
  const int id = blockIdx.x;
  const int xcd = id & 7, p = id >> 3;
  const int bh = xcd * 8 + (p >> 4);   // 8 bh per XCD -> K/V L2-resident
  const int qblk = p & 15;
  const int q0 = qblk * 128 + w * 32;  // wave owns q0..q0+31

  const short* qptr = q + ((size_t)bh * 2048 + q0 + r31) * 64 + h * 8;
  const short* kgl = kk + (size_t)bh * 2048 * 64;   // [2048][64]
  const short* vgl = vt + (size_t)bh * 64 * 2048;   // V^T [64][2048] (perm'd cols)

  // staging: thread stages rows srow, srow+8; source col pre-swizzled so LDS
  // image is [row][col ^ ((row&7)<<4)].
  const int srow = w * 16 + (lane >> 3);
  const int scol = ((lane & 7) * 8) ^ ((lane >> 3) << 3);  // shorts
  const int ldst = w * 2048;                               // bytes, +j*1024

  // Q fragments (pre-scaled by 0.125*log2e)
  bf16x8 qf[4];
#pragma unroll
  for (int dk = 0; dk < 4; ++dk) qf[dk] = *(const bf16x8*)(qptr + dk * 16);

  f32x16 o0, o1;
#pragma unroll
  for (int e = 0; e < 16; ++e) { o0[e] = 0.f; o1[e] = 0.f; }
  float ls[4];
#pragma unroll
  for (int e = 0; e < 4; ++e) ls[e] = 0.f;

  // prologue: stage tile 0 into buf 0
#pragma unroll
  for (int j = 0; j < 2; ++j) {
    gload_lds16(kgl + (size_t)(srow + j * 8) * 64 + scol, smem + ldst + j * 1024);
    gload_lds16(vgl + (size_t)(srow + j * 8) * 2048 + scol, smem + 8192 + ldst + j * 1024);
  }
  __syncthreads();

  int cur = 0;
  for (int t = 0; t < 2048; t += 64) {
    const char* Kb = smem + cur * 16384;
    const char* Vb = smem + cur * 16384 + 8192;

    // ---- prefetch next tile into other buffer ----
    if (t + 64 < 2048) {
      char* nb = (char*)smem + (cur ^ 1) * 16384;
#pragma unroll
      for (int j = 0; j < 2; ++j) {
        gload_lds16(kgl + (size_t)(t + 64 + srow + j * 8) * 64 + scol, nb + ldst + j * 1024);
        gload_lds16(vgl + (size_t)(srow + j * 8) * 2048 + (t + 64) + scol, nb + 8192 + ldst + j * 1024);
      }
    }

    // ---- K fragments from LDS (swizzled, conflict-free) ----
    bf16x8 kf0[4], kf1[4];
#pragma unroll
    for (int dk = 0; dk < 4; ++dk) {
      int cb = (dk * 32 + h * 16) ^ ((r31 & 7) << 4);
      kf0[dk] = *(const bf16x8*)(Kb + r31 * 128 + cb);
      kf1[dk] = *(const bf16x8*)(Kb + (32 + r31) * 128 + cb);
    }

    // ---- QK^T: S^T[k][q], two 32-key blocks (interleaved chains) ----
    f32x16 s0, s1;
#pragma unroll
    for (int e = 0; e < 16; ++e) { s0[e] = 0.f; s1[e] = 0.f; }
#pragma unroll
    for (int dk = 0; dk < 4; ++dk) {
      s0 = __builtin_amdgcn_mfma_f32_32x32x16_bf16(kf0[dk], qf[dk], s0, 0, 0, 0);
      s1 = __builtin_amdgcn_mfma_f32_32x32x16_bf16(kf1[dk], qf[dk], s1, 0, 0, 0);
    }

    // ---- max-free softmax: P = exp2(s) via v_exp_f32; l partials ----
#pragma unroll
    for (int e = 0; e < 16; ++e) {
      s0[e] = exp2_hw(s0[e]);
      s1[e] = exp2_hw(s1[e]);
    }
#pragma unroll
    for (int e = 0; e < 4; ++e) {
      float t0 = (s0[e] + s0[e + 4]) + (s0[e + 8] + s0[e + 12]);
      float t1 = (s1[e] + s1[e + 4]) + (s1[e + 8] + s1[e + 12]);
      ls[e] += t0 + t1;
    }

    // ---- P^T B-frags: direct cvt_pk (V pre-permuted; no exchange) ----
    bf16x8 pf0, pf1, pf2, pf3;
    BUILD_PF2(pf0, pf1, s0);
    BUILD_PF2(pf2, pf3, s1);

    // ---- O^T += V^T . P^T (vf in 2 chunks to cap live regs) ----
    {
      bf16x8 v00, v10, v01, v11;
      int cb0 = (0 * 32 + h * 16) ^ ((r31 & 7) << 4);
      int cb1 = (1 * 32 + h * 16) ^ ((r31 & 7) << 4);
      v00 = *(const bf16x8*)(Vb + r31 * 128 + cb0);
      v10 = *(const bf16x8*)(Vb + (32 + r31) * 128 + cb0);
      v01 = *(const bf16x8*)(Vb + r31 * 128 + cb1);
      v11 = *(const bf16x8*)(Vb + (32 + r31) * 128 + cb1);
      o0 = __builtin_amdgcn_mfma_f32_32x32x16_bf16(v00, pf0, o0, 0, 0, 0);
      o1 = __builtin_amdgcn_mfma_f32_32x32x16_bf16(v10, pf0, o1, 0, 0, 0);
      o0 = __builtin_amdgcn_mfma_f32_32x32x16_bf16(v01, pf1, o0, 0, 0, 0);
      o1 = __builtin_amdgcn_mfma_f32_32x32x16_bf16(v11, pf1, o1, 0, 0, 0);
    }
    {
      bf16x8 v02, v12, v03, v13;
      int cb2 = (2 * 32 + h * 16) ^ ((r31 & 7) << 4);
      int cb3 = (3 * 32 + h * 16) ^ ((r31 & 7) << 4);
      v02 = *(const bf16x8*)(Vb + r31 * 128 + cb2);
      v12 = *(const bf16x8*)(Vb + (32 + r31) * 128 + cb2);
      v03 = *(const bf16x8*)(Vb + r31 * 128 + cb3);
      v13 = *(const bf16x8*)(Vb + (32 + r31) * 128 + cb3);
      o0 = __builtin_amdgcn_mfma_f32_32x32x16_bf16(v02, pf2, o0, 0, 0, 0);
      o1 = __builtin_amdgcn_mfma_f32_32x32x16_bf16(v12, pf2, o1, 0, 0, 0);
      o0 = __builtin_amdgcn_mfma_f32_32x32x16_bf16(v03, pf3, o0, 0, 0, 0);
      o1 = __builtin_amdgcn_mfma_f32_32x32x16_bf16(v13, pf3, o1, 0, 0, 0);
    }

    __syncthreads();
    cur ^= 1;
  }

  // ---- epilogue: l tree + O/l -> ao bf16 [B,N,D] ----
  float lsum = (ls[0] + ls[1]) + (ls[2] + ls[3]);
  lsum += __shfl_xor(lsum, 32);

  const int b = bh >> 4, hd = bh & 15;
  float inv = 1.f / lsum;
  short* orow = ao + ((size_t)b * 2048 + q0 + r31) * 1024 + hd * 64;
#pragma unroll
  for (int s2 = 0; s2 < 4; ++s2) {
    s16x4 pk0, pk1;
#pragma unroll
    for (int r = 0; r < 4; ++r) {
      pk0[r] = f2bf(o0[4 * s2 + r] * inv);   // d = 8*s2 + 4*h + r
      pk1[r] = f2bf(o1[4 * s2 + r] * inv);   // d+32
    }
    *(s16x4*)(orow + 8 * s2 + 4 * h) = pk0;
    *(s16x4*)(orow + 32 + 8 * s2 + 4 * h) = pk1;
  }
}

// ---------------- launch ----------------
extern "C" void kernel_launch(void* const* d_in, const int* in_sizes, int n_in,
                              void* d_out, int out_size, void* d_ws, size_t ws_size,
                              hipStream_t stream) {
  const float* x = (const float*)d_in[0];
  const float* qkv_w = (const float*)d_in[1];
  const float* qkv_b = (const float*)d_in[2];
  const float* proj_w = (const float*)d_in[3];
  const float* proj_b = (const float*)d_in[4];
  float* out = (float*)d_out;

  char* ws = (char*)d_ws;
  short* xb    = (short*)(ws + 0);          // 16 MB  [8192][1024]
  short* wqkv  = (short*)(ws + 16777216);   // 6 MB   [3072][1024]
  short* wproj = (short*)(ws + 23068672);   // 2 MB   [1024][1024]
  short* qb    = (short*)(ws + 25165824);   // 16 MB  [B,H,N,Hd]
  short* kb    = (short*)(ws + 41943040);   // 16 MB  [B,H,N,Hd]
  short* vtb   = (short*)(ws + 58720256);   // 16 MB  [B,H,Hd,N] (perm'd cols)
  short* aob   = (short*)(ws + 75497472);   // 16 MB  [B,N,D]

  cvt_f32_bf16<<<8192, 256, 0, stream>>>(x, xb, 2097152);
  cvt_f32_bf16<<<3072, 256, 0, stream>>>(qkv_w, wqkv, 786432);
  cvt_f32_bf16<<<1024, 256, 0, stream>>>(proj_w, wproj, 262144);

  gemm_bt<0><<<dim3(24, 64), 256, 0, stream>>>(xb, wqkv, qkv_b, 1024, qb, kb, vtb, nullptr);
  attn_kernel<<<1024, 256, 0, stream>>>(qb, kb, vtb, aob);
  gemm_bt<1><<<dim3(8, 64), 256, 0, stream>>>(aob, wproj, proj_b, 1024, nullptr, nullptr, nullptr, out);
}